// Round 4
// baseline (419.628 us; speedup 1.0000x reference)
//
#include <hip/hip_runtime.h>

#define NB 512
#define NT 512
#define NL 64

__global__ void zero_out_kernel(float* out) { *out = 0.0f; }

// One wave (64 lanes) per batch element. Lane j owns state q_j and the
// exp(trans) column E[:,j] in 16 named float4 registers.
// R4: __launch_bounds__(64, 1) + amdgpu_waves_per_eu(1) -- without this the
// backend targets high occupancy and SPILLS the 64 e-values to scratch
// (VGPR_Count was 68; the per-step scratch round-trip was the bottleneck).
// Only 2 waves/CU exist physically (512 blocks / 256 CUs), so occupancy 1 is free.
__global__ __launch_bounds__(64, 1) __attribute__((amdgpu_waves_per_eu(1)))
void crf_nll_kernel(
    const float* __restrict__ emission,     // B,T,L
    const int*   __restrict__ target,       // B,T
    const float* __restrict__ mask,         // B,T
    const float* __restrict__ start_trans,  // L
    const float* __restrict__ trans,        // L,L
    const float* __restrict__ end_trans,    // L
    float* __restrict__ out)
{
  const int b = blockIdx.x;
  const int j = threadIdx.x;  // 0..63

  const float* em_b = emission + (size_t)b * NT * NL;
  const float* mk_b = mask + (size_t)b * NT;
  const int*   tg_b = target + (size_t)b * NT;

  // ---------------- path score (parallel over t, then wave-reduce) ----------
  float ps = 0.0f;
  #pragma unroll
  for (int c = 0; c < NT / 64; ++c) {
    int t = c * 64 + j;
    int cur = tg_b[t];
    float m  = mk_b[t];
    float mn = (t + 1 < NT) ? mk_b[t + 1] : 0.0f;
    if (t == 0) {
      ps += start_trans[cur] + em_b[cur];              // ps0, unconditional
    } else {
      int prev = tg_b[t - 1];
      if (m > 0.5f)
        ps += trans[prev * NL + cur] + em_b[(size_t)t * NL + cur];
      if (m - mn > 0.5f)                               // end_mask = m_t & !m_{t+1}
        ps += end_trans[cur];
    }
  }
  #pragma unroll
  for (int off = 32; off; off >>= 1) ps += __shfl_down(ps, off, 64);
  // lane 0 now holds the batch path score

  // -------- exp(trans) column in NAMED float4 registers --------
  #define MKECOL(K)                                          \
    float4 e##K;                                             \
    e##K.x = __expf(trans[(4 * K + 0) * NL + j]);            \
    e##K.y = __expf(trans[(4 * K + 1) * NL + j]);            \
    e##K.z = __expf(trans[(4 * K + 2) * NL + j]);            \
    e##K.w = __expf(trans[(4 * K + 3) * NL + j]);
  MKECOL(0)  MKECOL(1)  MKECOL(2)  MKECOL(3)
  MKECOL(4)  MKECOL(5)  MKECOL(6)  MKECOL(7)
  MKECOL(8)  MKECOL(9)  MKECOL(10) MKECOL(11)
  MKECOL(12) MKECOL(13) MKECOL(14) MKECOL(15)
  const float endt = __expf(end_trans[j]);

  __shared__ __align__(16) float qbuf[NL];
  const float4* qv = (const float4*)qbuf;

  float C = 0.0f;                               // accumulated log-scale
  float q = __expf(start_trans[j] + em_b[j]);   // t = 0 init (per ref)

  // 8-deep emission FIFO in named scalars: pf##U holds em[t][j] for t%8==U
  #define MKPF(U) float pf##U = em_b[(size_t)U * NL + j];
  MKPF(0) MKPF(1) MKPF(2) MKPF(3) MKPF(4) MKPF(5) MKPF(6) MKPF(7)

  #define DOT4(K, A0, A1, A2, A3) {                          \
    float4 x = qv[K];                                        \
    A0 = fmaf(x.x, e##K.x, A0);                              \
    A1 = fmaf(x.y, e##K.y, A1);                              \
    A2 = fmaf(x.z, e##K.z, A2);                              \
    A3 = fmaf(x.w, e##K.w, A3); }

  #define STEPU(U) {                                         \
    const int i = i8 + U;                                    \
    const int t = tb + i;                                    \
    float eem = __expf(pf##U);       /* off-chain exp */     \
    int tp = t + 8; if (tp > NT - 1) tp = NT - 1;            \
    pf##U = em_b[(size_t)tp * NL + j];  /* prefetch t+8 */   \
    __builtin_amdgcn_wave_barrier();                         \
    qbuf[j] = q;                                             \
    __builtin_amdgcn_wave_barrier();                         \
    float a0=0.f,a1=0.f,a2=0.f,a3=0.f;                       \
    float b0=0.f,b1=0.f,b2=0.f,b3=0.f;                       \
    DOT4(0,a0,a1,a2,a3)  DOT4(1,b0,b1,b2,b3)                 \
    DOT4(2,a0,a1,a2,a3)  DOT4(3,b0,b1,b2,b3)                 \
    DOT4(4,a0,a1,a2,a3)  DOT4(5,b0,b1,b2,b3)                 \
    DOT4(6,a0,a1,a2,a3)  DOT4(7,b0,b1,b2,b3)                 \
    DOT4(8,a0,a1,a2,a3)  DOT4(9,b0,b1,b2,b3)                 \
    DOT4(10,a0,a1,a2,a3) DOT4(11,b0,b1,b2,b3)                \
    DOT4(12,a0,a1,a2,a3) DOT4(13,b0,b1,b2,b3)                \
    DOT4(14,a0,a1,a2,a3) DOT4(15,b0,b1,b2,b3)                \
    float sm = ((a0+b0)+(a1+b1)) + ((a2+b2)+(a3+b3));        \
    float nxt = sm * eem;                                    \
    q = ((mbits >> i) & 1) ? nxt : q;                        \
    q = ((ebits >> i) & 1) ? q * endt : q; }

  #define RESCALE() {                                                         \
    float r = __uint_as_float(                                                \
        __builtin_amdgcn_readfirstlane(__float_as_uint(q)));                  \
    q *= __builtin_amdgcn_rcpf(r);                                            \
    C += __logf(r); }

  #pragma unroll 1
  for (int c = 0; c < 8; ++c) {
    const int tb = c * 64;
    // per-chunk masks as wave-uniform 64-bit ballot words
    float ml = mk_b[tb + j];
    int nidx = tb + j + 1;
    float mnext = (nidx < NT) ? mk_b[nidx] : 0.0f;
    unsigned long long mbits = __ballot(ml > 0.5f);
    unsigned long long ebits = __ballot(ml - mnext > 0.5f);
    if (c == 0) { mbits &= ~1ull; ebits &= ~1ull; }   // t=0 handled by init

    #pragma unroll 1
    for (int i8 = 0; i8 < 64; i8 += 8) {
      STEPU(0) STEPU(1) STEPU(2) STEPU(3)
      RESCALE()
      STEPU(4) STEPU(5) STEPU(6) STEPU(7)
      RESCALE()
    }
  }

  // ---------------- normalizer + output -------------------------------------
  float s = q;
  #pragma unroll
  for (int off = 32; off; off >>= 1) s += __shfl_xor(s, off, 64);
  if (j == 0) {
    float norm = __logf(s) + C;
    atomicAdd(out, (norm - ps) * (1.0f / (float)NB));
  }
}

extern "C" void kernel_launch(void* const* d_in, const int* in_sizes, int n_in,
                              void* d_out, int out_size, void* d_ws, size_t ws_size,
                              hipStream_t stream) {
  const float* emission    = (const float*)d_in[0];
  const int*   target      = (const int*)  d_in[1];
  const float* mask        = (const float*)d_in[2];
  const float* start_trans = (const float*)d_in[3];
  const float* trans       = (const float*)d_in[4];
  const float* end_trans   = (const float*)d_in[5];
  float* out = (float*)d_out;

  zero_out_kernel<<<1, 1, 0, stream>>>(out);
  crf_nll_kernel<<<NB, 64, 0, stream>>>(emission, target, mask, start_trans,
                                        trans, end_trans, out);
}

// Round 5
// 240.082 us; speedup vs baseline: 1.7479x; 1.7479x over previous
//
#include <hip/hip_runtime.h>

#define NB 512
#define NT 512
#define NL 64
#define L2E 1.4426950408889634f   // log2(e)
#define LN2 0.6931471805599453f   // ln(2)

__global__ void zero_out_kernel(float* out) { *out = 0.0f; }

// One wave (64 lanes) per batch element. Lane j owns state q_j and the
// exp2-domain trans column ecol[i] = exp2(l2e*trans[i][j]) in registers.
// Recursion: q'_j = (sum_i ecol_i q_i) * exp2(l2e*em_tj); rescale by lane-0
// value every 4 steps, accumulating C in log2 units.
// R5: NO libm-style calls anywhere (__expf/__logf replaced by
// __builtin_amdgcn_exp2f/__builtin_amdgcn_logf single instructions) -- calls
// impose ABI register constraints that forced ecol into spill slots
// (VGPR_Count pinned at 68 through R2-R4). waves_per_eu(1,1) opens the full
// VGPR budget (only 2 waves/CU exist physically: 512 blocks / 256 CUs).
__global__
__attribute__((amdgpu_flat_work_group_size(64, 64), amdgpu_waves_per_eu(1, 1)))
void crf_nll_kernel(
    const float* __restrict__ emission,     // B,T,L
    const int*   __restrict__ target,       // B,T
    const float* __restrict__ mask,         // B,T
    const float* __restrict__ start_trans,  // L
    const float* __restrict__ trans,        // L,L
    const float* __restrict__ end_trans,    // L
    float* __restrict__ out)
{
  const int b = blockIdx.x;
  const int j = threadIdx.x;  // 0..63

  const float* em_b = emission + (size_t)b * NT * NL;
  const float* mk_b = mask + (size_t)b * NT;
  const int*   tg_b = target + (size_t)b * NT;

  // ---------------- path score (parallel over t, then wave-reduce) ----------
  float ps = 0.0f;
  #pragma unroll
  for (int c = 0; c < NT / 64; ++c) {
    int t = c * 64 + j;
    int cur = tg_b[t];
    float m  = mk_b[t];
    float mn = (t + 1 < NT) ? mk_b[t + 1] : 0.0f;
    if (t == 0) {
      ps += start_trans[cur] + em_b[cur];              // ps0, unconditional
    } else {
      int prev = tg_b[t - 1];
      if (m > 0.5f)
        ps += trans[prev * NL + cur] + em_b[(size_t)t * NL + cur];
      if (m - mn > 0.5f)                               // end_mask = m_t & !m_{t+1}
        ps += end_trans[cur];
    }
  }
  #pragma unroll
  for (int off = 32; off; off >>= 1) ps += __shfl_down(ps, off, 64);
  // lane 0 now holds the batch path score

  // -------- exp2-domain trans column, intended to be register-resident ------
  float ecol[NL];
  #pragma unroll
  for (int i = 0; i < NL; ++i)
    ecol[i] = __builtin_amdgcn_exp2f(L2E * trans[i * NL + j]);  // coalesced
  const float endt = __builtin_amdgcn_exp2f(L2E * end_trans[j]);

  __shared__ __align__(16) float qbuf[NL];
  const float4* qv = (const float4*)qbuf;

  float C = 0.0f;   // accumulated scale, in log2 units
  float q = __builtin_amdgcn_exp2f(L2E * (start_trans[j] + em_b[j]));  // t=0

  // 8-deep emission FIFO, pre-scaled by log2(e): pf[t&7] = l2e*em[t][j]
  float pf[8];
  #pragma unroll
  for (int u = 0; u < 8; ++u) pf[u] = L2E * em_b[(size_t)u * NL + j];

  #pragma unroll 1
  for (int c = 0; c < 8; ++c) {
    const int tb = c * 64;
    // per-chunk masks as wave-uniform 64-bit ballot words
    float ml = mk_b[tb + j];
    int nidx = tb + j + 1;
    float mnext = (nidx < NT) ? mk_b[nidx] : 0.0f;
    unsigned long long mbits = __ballot(ml > 0.5f);
    unsigned long long ebits = __ballot(ml - mnext > 0.5f);
    if (c == 0) { mbits &= ~1ull; ebits &= ~1ull; }   // t=0 handled by init

    #pragma unroll 1
    for (int i8 = 0; i8 < 64; i8 += 8) {
      #pragma unroll
      for (int u = 0; u < 8; ++u) {
        const int i = i8 + u;
        float eem = __builtin_amdgcn_exp2f(pf[u]);     // off-chain exp
        int tp = tb + i + 8; if (tp > NT - 1) tp = NT - 1;
        pf[u] = L2E * em_b[(size_t)tp * NL + j];       // prefetch t+8
        qbuf[j] = q;                                   // same-object alias
        float4 x[16];                                  //   => ordered by HW
        #pragma unroll
        for (int k = 0; k < 16; ++k) x[k] = qv[k];     // reads grouped first
        float a0 = 0.f, a1 = 0.f, a2 = 0.f, a3 = 0.f;
        float b0 = 0.f, b1 = 0.f, b2 = 0.f, b3 = 0.f;
        #pragma unroll
        for (int k = 0; k < 16; k += 2) {
          a0 = fmaf(x[k].x,     ecol[4 * k + 0], a0);
          a1 = fmaf(x[k].y,     ecol[4 * k + 1], a1);
          a2 = fmaf(x[k].z,     ecol[4 * k + 2], a2);
          a3 = fmaf(x[k].w,     ecol[4 * k + 3], a3);
          b0 = fmaf(x[k + 1].x, ecol[4 * k + 4], b0);
          b1 = fmaf(x[k + 1].y, ecol[4 * k + 5], b1);
          b2 = fmaf(x[k + 1].z, ecol[4 * k + 6], b2);
          b3 = fmaf(x[k + 1].w, ecol[4 * k + 7], b3);
        }
        float sm = ((a0 + b0) + (a1 + b1)) + ((a2 + b2) + (a3 + b3));
        float nxt = sm * eem;
        q = ((mbits >> i) & 1) ? nxt : q;
        q = ((ebits >> i) & 1) ? q * endt : q;
        if ((u & 3) == 3) {                            // rescale every 4 steps
          float r = __uint_as_float(
              __builtin_amdgcn_readfirstlane(__float_as_uint(q)));
          q *= __builtin_amdgcn_rcpf(r);
          C += __builtin_amdgcn_logf(r);               // log2(r)
        }
      }
    }
  }

  // ---------------- normalizer + output -------------------------------------
  float s = q;
  #pragma unroll
  for (int off = 32; off; off >>= 1) s += __shfl_xor(s, off, 64);
  if (j == 0) {
    float norm = (__builtin_amdgcn_logf(s) + C) * LN2;  // back to natural log
    atomicAdd(out, (norm - ps) * (1.0f / (float)NB));
  }
}

extern "C" void kernel_launch(void* const* d_in, const int* in_sizes, int n_in,
                              void* d_out, int out_size, void* d_ws, size_t ws_size,
                              hipStream_t stream) {
  const float* emission    = (const float*)d_in[0];
  const int*   target      = (const int*)  d_in[1];
  const float* mask        = (const float*)d_in[2];
  const float* start_trans = (const float*)d_in[3];
  const float* trans       = (const float*)d_in[4];
  const float* end_trans   = (const float*)d_in[5];
  float* out = (float*)d_out;

  zero_out_kernel<<<1, 1, 0, stream>>>(out);
  crf_nll_kernel<<<NB, 64, 0, stream>>>(emission, target, mask, start_trans,
                                        trans, end_trans, out);
}